// Round 1
// baseline (375.534 us; speedup 1.0000x reference)
//
#include <hip/hip_runtime.h>
#include <cstdint>
#include <cstddef>

typedef float  v4f __attribute__((ext_vector_type(4)));
typedef float  v4f_cd __attribute__((ext_vector_type(4)));
typedef short  v8s __attribute__((ext_vector_type(8)));
typedef int    v4i __attribute__((ext_vector_type(4)));
typedef unsigned int v2u __attribute__((ext_vector_type(2)));

#define BB 8
#define NN 2048
#define DD 128
#define TI 64
#define NEGV (-9e15f)

__device__ __forceinline__ unsigned short f2bf(float x) {
  unsigned u = __float_as_uint(x);
  u = u + 0x7FFFu + ((u >> 16) & 1u);   // round-to-nearest-even
  return (unsigned short)(u >> 16);
}

// K1: Wh = h @ W (fp32), Wh1 = Wh·a[:128], Wh2 = Wh·a[128:], and WhbT = bf16(Wh)^T per batch.
// One block per (b, 64-row tile). 256 threads: c = tid&31 -> cols 4c..4c+3, g = tid>>5 -> rows 8g..8g+7.
__global__ __launch_bounds__(256) void gat_k1(
    const float* __restrict__ h, const float* __restrict__ W, const float* __restrict__ a,
    short* __restrict__ whbT, float* __restrict__ wh1g, float* __restrict__ wh2g)
{
  __shared__ __align__(16) float hs[TI * DD];                 // 32 KB
  __shared__ __align__(16) unsigned short staging[DD * 80];   // 20 KB (stride 80 keeps 16B align)

  const int tid = threadIdx.x;
  const int b = blockIdx.y;
  const int i0 = blockIdx.x * TI;

  // load h tile (64 x 128 fp32), coalesced float4
  const v4f* hg = (const v4f*)(h + (size_t)(b * NN + i0) * DD);
  #pragma unroll
  for (int v = 0; v < 8; v++) {
    int idx = v * 256 + tid;
    ((v4f*)hs)[idx] = hg[idx];
  }
  __syncthreads();

  const int c = tid & 31;
  const int g = tid >> 5;
  const v4f* Wg4 = (const v4f*)W;

  v4f acc[8];
  #pragma unroll
  for (int r = 0; r < 8; r++) acc[r] = (v4f){0.f, 0.f, 0.f, 0.f};

  for (int k0 = 0; k0 < DD; k0 += 4) {
    v4f w0 = Wg4[(k0 + 0) * 32 + c];
    v4f w1 = Wg4[(k0 + 1) * 32 + c];
    v4f w2 = Wg4[(k0 + 2) * 32 + c];
    v4f w3 = Wg4[(k0 + 3) * 32 + c];
    #pragma unroll
    for (int r = 0; r < 8; r++) {
      v4f hv = *(const v4f*)&hs[(g * 8 + r) * DD + k0];
      acc[r] += hv.x * w0 + hv.y * w1 + hv.z * w2 + hv.w * w3;
    }
  }

  // Wh1/Wh2 partial dot with a, reduce across the 32 threads (c) sharing a row group
  v4f a1 = ((const v4f*)a)[c];
  v4f a2 = ((const v4f*)a)[32 + c];
  #pragma unroll
  for (int r = 0; r < 8; r++) {
    float p1 = acc[r].x * a1.x + acc[r].y * a1.y + acc[r].z * a1.z + acc[r].w * a1.w;
    float p2 = acc[r].x * a2.x + acc[r].y * a2.y + acc[r].z * a2.z + acc[r].w * a2.w;
    #pragma unroll
    for (int off = 16; off > 0; off >>= 1) {
      p1 += __shfl_xor(p1, off);
      p2 += __shfl_xor(p2, off);
    }
    if (c == 0) {
      wh1g[b * NN + i0 + g * 8 + r] = p1;
      wh2g[b * NN + i0 + g * 8 + r] = p2;
    }
    #pragma unroll
    for (int cc = 0; cc < 4; cc++)
      staging[(c * 4 + cc) * 80 + g * 8 + r] = f2bf(acc[r][cc]);
  }
  __syncthreads();

  // write WhbT[b][t][i0..i0+63] coalesced, 16B per lane
  #pragma unroll
  for (int v = 0; v < 4; v++) {
    int idx = v * 256 + tid;     // 1024 vec8 total
    int t = idx >> 3;
    int i8 = idx & 7;
    v8s val = *(const v8s*)&staging[t * 80 + i8 * 8];
    *(v8s*)(whbT + (size_t)b * DD * NN + (size_t)t * NN + i0 + i8 * 8) = val;
  }
}

// K2: fused masked-softmax (write attention) + h' = att @ Wh via bf16 MFMA + residual.
// One block per (b, 64-row tile). 256 threads = 4 waves.
__global__ __launch_bounds__(256) void gat_k2(
    const float* __restrict__ h, const int* __restrict__ adj,
    const short* __restrict__ whbT, const float* __restrict__ wh1g,
    const float* __restrict__ wh2g, float* __restrict__ out,
    float* __restrict__ attout)
{
  __shared__ __align__(16) float wh2s[NN];            // 8 KB
  __shared__ float wh1s[TI];
  __shared__ unsigned int maskw[TI * 64];             // 16 KB adj bitmask
  __shared__ float m_s[TI];
  __shared__ float rs_s[TI];
  __shared__ __align__(16) unsigned short atile[TI * 72];  // 64 rows x 64 j (stride 72), 9 KB

  const int tid = threadIdx.x;
  const int lane = tid & 63;
  const int wid = tid >> 6;
  const int b = blockIdx.y;
  const int i0 = blockIdx.x * TI;

  for (int t = tid; t < NN; t += 256) wh2s[t] = wh2g[b * NN + t];
  if (tid < TI) wh1s[tid] = wh1g[b * NN + i0 + tid];
  __syncthreads();

  // ---- Phase 1: adj read (once), row max & sum, mask bitpack. Wave w owns rows w, w+4, ...
  for (int ii = wid; ii < TI; ii += 4) {
    const v4i* arow = (const v4i*)(adj + (size_t)(b * NN + i0 + ii) * NN);
    const float wh1v = wh1s[ii];
    float e[32];
    float m = -INFINITY;
    unsigned mbits = 0u;
    #pragma unroll
    for (int u = 0; u < 8; u++) {
      v4i av = arow[u * 64 + lane];
      v4f w2v = ((const v4f*)wh2s)[u * 64 + lane];
      #pragma unroll
      for (int q = 0; q < 4; q++) {
        bool mk = av[q] > 0;
        float x = wh1v + w2v[q];
        float ev = mk ? (x > 0.f ? x : 0.2f * x) : NEGV;
        e[u * 4 + q] = ev;
        m = fmaxf(m, ev);
        mbits |= (mk ? 1u : 0u) << (u * 4 + q);
      }
    }
    maskw[ii * 64 + lane] = mbits;
    #pragma unroll
    for (int off = 32; off > 0; off >>= 1) m = fmaxf(m, __shfl_xor(m, off));
    float s = 0.f;
    #pragma unroll
    for (int k = 0; k < 32; k++) s += __expf(e[k] - m);
    #pragma unroll
    for (int off = 32; off > 0; off >>= 1) s += __shfl_xor(s, off);
    if (lane == 0) { m_s[ii] = m; rs_s[ii] = 1.f / s; }
  }
  __syncthreads();

  // ---- Phase 2: per 64-wide j chunk: att (fp32 write + bf16 LDS) then MFMA accumulate.
  float* attrow_base = attout + (size_t)(b * NN + i0) * NN;
  const short* whbT_b = whbT + (size_t)b * DD * NN;
  const int m16 = lane & 15;
  const int quad = lane >> 4;

  v4f_cd acc[8];
  #pragma unroll
  for (int t = 0; t < 8; t++) acc[t] = (v4f_cd){0.f, 0.f, 0.f, 0.f};

  for (int jc = 0; jc < 32; jc++) {
    const int j0 = jc * 64;
    const int ubit = (jc >> 2) << 2;  // = (j>>8)*4, constant within chunk
    #pragma unroll
    for (int r = 0; r < 4; r++) {
      int idx = r * 256 + tid;        // 1024 float4 = 64 rows x 16 groups
      int i = idx >> 4;
      int jq = idx & 15;
      unsigned mw = maskw[i * 64 + ((jc * 16 + jq) & 63)];
      float wh1v = wh1s[i];
      float mi = m_s[i];
      float rsi = rs_s[i];
      v4f av;
      unsigned short ab[4];
      #pragma unroll
      for (int q = 0; q < 4; q++) {
        int j = j0 + jq * 4 + q;
        float x = wh1v + wh2s[j];
        float ev = ((mw >> (ubit + q)) & 1u) ? (x > 0.f ? x : 0.2f * x) : NEGV;
        float at = __expf(ev - mi) * rsi;
        av[q] = at;
        ab[q] = f2bf(at);
      }
      *(v4f*)(attrow_base + (size_t)i * NN + j0 + jq * 4) = av;
      v2u uv;
      uv[0] = (unsigned)ab[0] | ((unsigned)ab[1] << 16);
      uv[1] = (unsigned)ab[2] | ((unsigned)ab[3] << 16);
      *(v2u*)&atile[i * 72 + jq * 4] = uv;
    }
    __syncthreads();

    // MFMA: wave w owns rows [w*16, w*16+16), all 8 d-tiles. K = 64 per chunk (2 steps of 32).
    #pragma unroll
    for (int ks = 0; ks < 2; ks++) {
      v8s af = *(const v8s*)&atile[(wid * 16 + m16) * 72 + ks * 32 + quad * 8];
      const short* bb = whbT_b + (size_t)m16 * NN + j0 + ks * 32 + quad * 8;
      #pragma unroll
      for (int t = 0; t < 8; t++) {
        v8s bf = *(const v8s*)(bb + (size_t)t * 16 * NN);
        acc[t] = __builtin_amdgcn_mfma_f32_16x16x32_bf16(af, bf, acc[t], 0, 0, 0);
      }
    }
    __syncthreads();
  }

  // ---- Epilogue: out = h + h'. C/D layout: col = lane&15, row = quad*4 + reg.
  const int orow0 = i0 + wid * 16 + quad * 4;
  #pragma unroll
  for (int t = 0; t < 8; t++) {
    #pragma unroll
    for (int r = 0; r < 4; r++) {
      size_t gidx = ((size_t)(b * NN + orow0 + r)) * DD + t * 16 + m16;
      out[gidx] = h[gidx] + acc[t][r];
    }
  }
}

extern "C" void kernel_launch(void* const* d_in, const int* in_sizes, int n_in,
                              void* d_out, int out_size, void* d_ws, size_t ws_size,
                              hipStream_t stream) {
  const float* h  = (const float*)d_in[0];
  const int* adj  = (const int*)d_in[1];
  const float* W  = (const float*)d_in[2];
  const float* a  = (const float*)d_in[3];

  float* out    = (float*)d_out;
  float* attout = out + (size_t)BB * NN * DD;

  short* whbT = (short*)d_ws;                                    // 4 MB bf16 Wh^T per batch
  float* wh1  = (float*)((char*)d_ws + (size_t)BB * DD * NN * 2);
  float* wh2  = wh1 + BB * NN;

  gat_k1<<<dim3(NN / TI, BB), 256, 0, stream>>>(h, W, a, whbT, wh1, wh2);
  gat_k2<<<dim3(NN / TI, BB), 256, 0, stream>>>(h, adj, whbT, wh1, wh2, out, attout);
}